// Round 8
// baseline (562.426 us; speedup 1.0000x reference)
//
#include <hip/hip_runtime.h>
#include <math.h>

// GCN forward: 2x GCNConv (20->16->2) + ReLU + log_softmax
// N=100000 nodes, E=6400000 edges.
//
// Per layer (exact algebra of PyG GCNConv w/ self-loops):
//   y[i]   = (x[i] @ W) * dinv[i]
//   s[i]   = sum_{c in in-neighbors(i)} y[c]     (row-sorted CSR, register accum, NO atomics)
//   out[i] = dinv[i]*(s[i] + y[i]) + b           (self-loop = dinv^2 * xw)
//
// Contention/amplification lessons baked in:
//   - R3: global atomic throughput scales with ADDRESS CARDINALITY (~11ns/op
//     same-line serialization). deg histogram over 100K addresses is fine;
//     hundreds of counters is not.
//   - R4: per-edge-per-feature LDS float atomics are a wall -> row-sort once.
//   - R5/R6/R7: ANY scattered 4B global writes suffer 4-7x HBM write
//     amplification under concurrent streaming reads (partial lines evicted
//     from L2 before filling) -- block-local windows do NOT fix it. The only
//     guaranteed amp=1 write is a coalesced burst. R8: passA scatters into a
//     64KB LDS stage, then burst-copies out. (Exception: passB's final CSR
//     placement into 32KB/block regions completes fast enough -> measured
//     amp=1.0 in R7; kept.)
//   - R6: y1 gather table in bf16 (3.2MB) -> fits per-XCD 4MiB L2.
//
// Pipeline: deg (global hist) -> scan1/2/3 (rowptr+dinv) -> passA (LDS-staged
//   multisplit into block-major csrtmp + lbt table) -> passB (offset-table
//   driven stitch + in-bucket sort -> row-sorted csr) -> xw1(bf16) ->
//   gather16 -> hw2 -> gather2.

#define XF 20
#define F1 16
#define F2 2
#define RPB 128           // rows per bucket (1<<7)
#define KMAX 800          // max buckets (N <= 102400)
#define KP   784          // lbt row stride (>= K+1)
#define TILE 16384        // edges per passA block
#define NJMAX 400         // max passA blocks/segments (E <= 6553600)
#define CAP 9216          // passB LDS stage (mean 8192, sigma ~90 -> +11 sigma)

__device__ __forceinline__ unsigned bf16rne(float f) {
    unsigned u = __float_as_uint(f);
    return (u + 0x7FFFu + ((u >> 16) & 1u)) >> 16;
}
__device__ __forceinline__ float bflo(unsigned w) { return __uint_as_float(w << 16); }
__device__ __forceinline__ float bfhi(unsigned w) { return __uint_as_float(w & 0xFFFF0000u); }

// Per-row in-degree histogram: 6.4M global atomics over 100K addresses (safe
// cardinality per R3). int4 loads for the index stream.
__global__ void deg_kernel(const int* __restrict__ rows, int E, int* __restrict__ deg) {
    int idx = blockIdx.x * blockDim.x + threadIdx.x;
    int n4 = E >> 2;
    if (idx < n4) {
        int4 r = ((const int4*)rows)[idx];
        atomicAdd(&deg[r.x], 1);
        atomicAdd(&deg[r.y], 1);
        atomicAdd(&deg[r.z], 1);
        atomicAdd(&deg[r.w], 1);
    }
    int tail = n4 << 2;
    if (idx < (E - tail)) atomicAdd(&deg[rows[tail + idx]], 1);
}

// ---- 3-kernel exclusive scan over deg -> rowptr, plus dinv (R2-proven) ----
__global__ void scan1_kernel(const int* __restrict__ deg, int* __restrict__ partials, int N) {
    __shared__ int tmp[256];
    int t = threadIdx.x;
    int i = blockIdx.x * 256 + t;
    tmp[t] = (i < N) ? deg[i] : 0;
    __syncthreads();
    for (int s = 128; s > 0; s >>= 1) {
        if (t < s) tmp[t] += tmp[t + s];
        __syncthreads();
    }
    if (t == 0) partials[blockIdx.x] = tmp[0];
}

__global__ void scan2_kernel(int* __restrict__ partials, int nb, int* __restrict__ rowptr,
                             int N, int E) {
    __shared__ int tmp[1024];
    int t = threadIdx.x;
    int v = (t < nb) ? partials[t] : 0;
    tmp[t] = v;
    __syncthreads();
    for (int d = 1; d < 1024; d <<= 1) {
        int u = (t >= d) ? tmp[t - d] : 0;
        __syncthreads();
        tmp[t] += u;
        __syncthreads();
    }
    if (t < nb) partials[t] = tmp[t] - v;  // exclusive
    if (t == 0) rowptr[N] = E;
}

__global__ void scan3_kernel(const int* __restrict__ deg, const int* __restrict__ partials,
                             int* __restrict__ rowptr, float* __restrict__ dinv, int N) {
    __shared__ int tmp[256];
    int t = threadIdx.x;
    int i = blockIdx.x * 256 + t;
    int v = (i < N) ? deg[i] : 0;
    tmp[t] = v;
    __syncthreads();
    for (int d = 1; d < 256; d <<= 1) {
        int u = (t >= d) ? tmp[t - d] : 0;
        __syncthreads();
        tmp[t] += u;
        __syncthreads();
    }
    if (i < N) {
        rowptr[i] = partials[blockIdx.x] + tmp[t] - v;     // exclusive scan
        dinv[i] = rsqrtf((float)v + 1.0f);                 // +1 self-loop
    }
}

// Multisplit with LDS staging: per-block LDS hist -> local scan -> scatter
// packed (c<<7)|(r&127) into 64KB LDS stage (bucket-major) -> coalesced BURST
// to csrtmp[e0..e1] (amp=1 by construction). lbt[blk][k] = local bucket start,
// lbt[blk][K] = tile count. Zero global atomics.
__global__ __launch_bounds__(512) void passA_kernel(const int* __restrict__ rows,
                                                    const int* __restrict__ cols,
                                                    int* __restrict__ lbt,
                                                    unsigned int* __restrict__ csrtmp,
                                                    int E, int K) {
    __shared__ unsigned int stage[TILE];  // 64KB
    __shared__ int hist[KMAX];            // counts -> cursors
    __shared__ int lbase[KMAX];
    __shared__ int tsum[512];
    int t = threadIdx.x;
    int bj = blockIdx.x;
    for (int k = t; k < K; k += 512) hist[k] = 0;
    __syncthreads();
    int e0 = bj * TILE;
    int e1 = min(e0 + TILE, E);
    int n = e1 - e0;
    for (int e = e0 + t; e < e1; e += 512)
        atomicAdd(&hist[rows[e] >> 7], 1);
    __syncthreads();
    // block-wide exclusive scan over K buckets (2 per thread)
    int k0 = 2 * t, k1 = 2 * t + 1;
    int v0 = (k0 < K) ? hist[k0] : 0;
    int v1 = (k1 < K) ? hist[k1] : 0;
    int s = v0 + v1;
    tsum[t] = s;
    __syncthreads();
    for (int d = 1; d < 512; d <<= 1) {
        int u = (t >= d) ? tsum[t - d] : 0;
        __syncthreads();
        tsum[t] += u;
        __syncthreads();
    }
    int run = tsum[t] - s;
    long long lrow = (long long)bj * KP;
    if (k0 < K) { lbase[k0] = run;      hist[k0] = run;      lbt[lrow + k0] = run; }
    if (k1 < K) { lbase[k1] = run + v0; hist[k1] = run + v0; lbt[lrow + k1] = run + v0; }
    if (t == 0) lbt[lrow + K] = n;
    __syncthreads();
    // scatter into LDS stage (cursor = hist, starts at lbase)
    for (int e = e0 + t; e < e1; e += 512) {
        int r = rows[e];
        int b = r >> 7;
        int pos = atomicAdd(&hist[b], 1);
        stage[pos] = ((unsigned int)cols[e] << 7) | (unsigned int)(r & 127);
    }
    __syncthreads();
    // coalesced burst out
    for (int ss = t; ss < n; ss += 512)
        csrtmp[(size_t)e0 + ss] = stage[ss];
}

// One block per bucket: load all segment offsets up-front (no dependent
// chains), prefix-scan lengths -> stage positions, burst-gather segments into
// LDS, then place row-sorted into final csr via rowptr (1 LDS atomic/edge).
__global__ __launch_bounds__(256) void passB_kernel(const int* __restrict__ lbt,
                                                    const unsigned int* __restrict__ csrtmp,
                                                    const int* __restrict__ rowptr,
                                                    unsigned int* __restrict__ csr,
                                                    int N, int K, int E, int nj) {
    __shared__ unsigned int stage[CAP];
    __shared__ int segoff[NJMAX];
    __shared__ int stagepos[NJMAX + 1];
    __shared__ int rp[RPB];
    __shared__ int cur[RPB];
    __shared__ int tsum[256];
    int b = blockIdx.x, t = threadIdx.x;
    int lo = b << 7;
    if (t < RPB) {
        int i = lo + t;
        rp[t] = (i < N) ? rowptr[i] : E;
        cur[t] = 0;
    }
    // load 2 segments per thread: offsets (8B contiguous read per seg)
    int a0 = 2 * t, a1 = 2 * t + 1;
    int la = 0, lb2 = 0;
    if (a0 < nj) {
        const int* lp = lbt + (long long)a0 * KP + b;
        int o0 = lp[0], o1 = lp[1];
        segoff[a0] = o0; la = o1 - o0;
    }
    if (a1 < nj) {
        const int* lp = lbt + (long long)a1 * KP + b;
        int o0 = lp[0], o1 = lp[1];
        segoff[a1] = o0; lb2 = o1 - o0;
    }
    int s = la + lb2;
    tsum[t] = s;
    __syncthreads();
    for (int d = 1; d < 256; d <<= 1) {
        int u = (t >= d) ? tsum[t - d] : 0;
        __syncthreads();
        tsum[t] += u;
        __syncthreads();
    }
    int run = tsum[t] - s;
    if (a0 < nj) stagepos[a0] = run;
    if (a1 < nj) stagepos[a1] = run + la;
    if (t == 255) stagepos[nj] = tsum[255];
    __syncthreads();
    int cnt = min(stagepos[nj], CAP);
    // stage-in: 8 sub-waves of 32 lanes, segments round-robin
    int sw = t >> 5, ln = t & 31;
    for (int seg = sw; seg < nj; seg += 8) {
        int sp = stagepos[seg];
        int len = stagepos[seg + 1] - sp;
        if (sp + len > CAP) len = max(0, CAP - sp);  // safety clamp
        size_t src = (size_t)seg * TILE + segoff[seg];
        for (int e2 = ln; e2 < len; e2 += 32)
            stage[sp + e2] = csrtmp[src + e2];
    }
    __syncthreads();
    // row-sorted placement (writes confined to this bucket's 32KB region;
    // measured amp=1.0 in R7)
    for (int ss = t; ss < cnt; ss += 256) {
        unsigned int p = stage[ss];
        int rr = (int)(p & 127u);
        int dst = rp[rr] + atomicAdd(&cur[rr], 1);
        csr[dst] = p >> 7;
    }
}

// y1h[i][j] = bf16( (sum_k x[i][k] * W1[k][j]) * dinv[i] )  -- 32B/row table
__global__ void xw1_kernel(const float* __restrict__ x, const float* __restrict__ W1,
                           const float* __restrict__ dinv, unsigned int* __restrict__ y1h,
                           int N) {
    __shared__ float Ws[XF * F1];
    for (int k = threadIdx.x; k < XF * F1; k += blockDim.x) Ws[k] = W1[k];
    __syncthreads();
    int i = blockIdx.x * blockDim.x + threadIdx.x;
    if (i >= N) return;
    const float4* xv = (const float4*)(x + (size_t)i * XF);
    float xr[XF];
    #pragma unroll
    for (int q = 0; q < 5; q++) {
        float4 v = xv[q];
        xr[q*4+0] = v.x; xr[q*4+1] = v.y; xr[q*4+2] = v.z; xr[q*4+3] = v.w;
    }
    float d = dinv[i];
    float out[F1];
    #pragma unroll
    for (int j = 0; j < F1; j++) {
        float a = 0.f;
        #pragma unroll
        for (int k = 0; k < XF; k++) a += xr[k] * Ws[k * F1 + j];
        out[j] = a * d;
    }
    unsigned int w[8];
    #pragma unroll
    for (int q = 0; q < 8; q++)
        w[q] = bf16rne(out[2*q]) | (bf16rne(out[2*q+1]) << 16);
    uint4* o = (uint4*)(y1h + (size_t)i * 8);
    o[0] = make_uint4(w[0], w[1], w[2], w[3]);
    o[1] = make_uint4(w[4], w[5], w[6], w[7]);
}

// One wave per row: 2 lanes/edge (8 bf16 features each), 32 edges in flight,
// register accumulation, shfl-xor reduce, fused ReLU. Zero atomics.
__global__ __launch_bounds__(256) void gather16_kernel(const int* __restrict__ rowptr,
                                                       const unsigned int* __restrict__ csr,
                                                       const unsigned int* __restrict__ y1h,
                                                       const float* __restrict__ dinv,
                                                       const float* __restrict__ b1,
                                                       float* __restrict__ h, int N) {
    int wave = threadIdx.x >> 6;
    int lane = threadIdx.x & 63;
    int i = blockIdx.x * 4 + wave;
    if (i >= N) return;
    int half = lane & 1, es = lane >> 1;
    int start = rowptr[i], end = rowptr[i + 1];
    const uint4* Y = (const uint4*)y1h;
    float acc[8] = {0.f, 0.f, 0.f, 0.f, 0.f, 0.f, 0.f, 0.f};
    for (int slot = start + es; slot < end; slot += 32) {
        int c = (int)csr[slot];
        uint4 w = Y[(size_t)c * 2 + half];
        acc[0] += bflo(w.x); acc[1] += bfhi(w.x);
        acc[2] += bflo(w.y); acc[3] += bfhi(w.y);
        acc[4] += bflo(w.z); acc[5] += bfhi(w.z);
        acc[6] += bflo(w.w); acc[7] += bfhi(w.w);
    }
    #pragma unroll
    for (int m = 2; m <= 32; m <<= 1) {
        #pragma unroll
        for (int k = 0; k < 8; k++) acc[k] += __shfl_xor(acc[k], m);
    }
    if (lane < 2) {
        float d = dinv[i];
        uint4 w = Y[(size_t)i * 2 + lane];
        float self[8] = { bflo(w.x), bfhi(w.x), bflo(w.y), bfhi(w.y),
                          bflo(w.z), bfhi(w.z), bflo(w.w), bfhi(w.w) };
        float4 bl = ((const float4*)b1)[lane * 2];
        float4 bh = ((const float4*)b1)[lane * 2 + 1];
        float bb[8] = { bl.x, bl.y, bl.z, bl.w, bh.x, bh.y, bh.z, bh.w };
        float v[8];
        #pragma unroll
        for (int k = 0; k < 8; k++)
            v[k] = fmaxf(d * (acc[k] + self[k]) + bb[k], 0.f);
        float4* ho = (float4*)(h + (size_t)i * F1 + lane * 8);
        ho[0] = make_float4(v[0], v[1], v[2], v[3]);
        ho[1] = make_float4(v[4], v[5], v[6], v[7]);
    }
}

// y2[i][j] = (sum_k h[i][k] * W2[k][j]) * dinv[i]
__global__ void hw2_kernel(const float* __restrict__ h, const float* __restrict__ W2,
                           const float* __restrict__ dinv, float* __restrict__ y2, int N) {
    __shared__ float Ws[F1 * F2];
    if (threadIdx.x < F1 * F2) Ws[threadIdx.x] = W2[threadIdx.x];
    __syncthreads();
    int i = blockIdx.x * blockDim.x + threadIdx.x;
    if (i >= N) return;
    const float4* hv = (const float4*)(h + (size_t)i * F1);
    float a0 = 0.f, a1 = 0.f;
    #pragma unroll
    for (int q = 0; q < 4; q++) {
        float4 v = hv[q];
        a0 += v.x * Ws[(q*4+0)*2] + v.y * Ws[(q*4+1)*2] + v.z * Ws[(q*4+2)*2] + v.w * Ws[(q*4+3)*2];
        a1 += v.x * Ws[(q*4+0)*2+1] + v.y * Ws[(q*4+1)*2+1] + v.z * Ws[(q*4+2)*2+1] + v.w * Ws[(q*4+3)*2+1];
    }
    float d = dinv[i];
    ((float2*)y2)[i] = make_float2(a0 * d, a1 * d);
}

// One wave per row: 1 lane/edge float2 gather, register accum, shfl reduce,
// fused log_softmax. Zero atomics. y2 = 800KB -> L2-resident.
__global__ __launch_bounds__(256) void gather2_kernel(const int* __restrict__ rowptr,
                                                      const unsigned int* __restrict__ csr,
                                                      const float* __restrict__ y2,
                                                      const float* __restrict__ dinv,
                                                      const float* __restrict__ b2,
                                                      float* __restrict__ out, int N) {
    int wave = threadIdx.x >> 6;
    int lane = threadIdx.x & 63;
    int i = blockIdx.x * 4 + wave;
    if (i >= N) return;
    int start = rowptr[i], end = rowptr[i + 1];
    float a0 = 0.f, a1 = 0.f;
    for (int slot = start + lane; slot < end; slot += 64) {
        int c = (int)csr[slot];
        float2 v = ((const float2*)y2)[c];
        a0 += v.x;
        a1 += v.y;
    }
    #pragma unroll
    for (int m = 32; m > 0; m >>= 1) {
        a0 += __shfl_xor(a0, m);
        a1 += __shfl_xor(a1, m);
    }
    if (lane == 0) {
        float d = dinv[i];
        float2 yi = ((const float2*)y2)[i];
        float v0 = d * (a0 + yi.x) + b2[0];
        float v1 = d * (a1 + yi.y) + b2[1];
        float mm = fmaxf(v0, v1);
        float lse = mm + logf(expf(v0 - mm) + expf(v1 - mm));
        ((float2*)out)[i] = make_float2(v0 - lse, v1 - lse);
    }
}

static inline size_t align256(size_t x) { return (x + 255) & ~(size_t)255; }

extern "C" void kernel_launch(void* const* d_in, const int* in_sizes, int n_in,
                              void* d_out, int out_size, void* d_ws, size_t ws_size,
                              hipStream_t stream) {
    const float* x  = (const float*)d_in[0];
    const int*   ei = (const int*)d_in[1];
    const float* W1 = (const float*)d_in[2];
    const float* b1 = (const float*)d_in[3];
    const float* W2 = (const float*)d_in[4];
    const float* b2 = (const float*)d_in[5];
    float* out = (float*)d_out;

    const int N = in_sizes[0] / XF;
    const int E = in_sizes[1] / 2;
    const int* rows = ei;
    const int* cols = ei + E;
    const int K = (N + RPB - 1) >> 7;        // 782 buckets for N=100000
    const int nj = (E + TILE - 1) / TILE;    // 391 passA blocks/segments

    // Workspace; zero-region first (deg only), one 400KB memset.
    char* ws = (char*)d_ws;
    size_t off = 0;
    int*   deg     = (int*)(ws + off);   off = align256(off + (size_t)N * 4);
    size_t zero_bytes = off;
    int*   parts   = (int*)(ws + off);   off = align256(off + 1024 * 4);
    int*   rowptr  = (int*)(ws + off);   off = align256(off + (size_t)(N + 1) * 4);
    float* dinv    = (float*)(ws + off); off = align256(off + (size_t)N * 4);
    int*   lbt     = (int*)(ws + off);   off = align256(off + (size_t)nj * KP * 4);
    unsigned int* csr = (unsigned int*)(ws + off); off = align256(off + (size_t)E * 4);
    // csrtmp is dead after passB -> y1h/h/y2 alias its region.
    size_t tmp0 = off;
    unsigned int* csrtmp = (unsigned int*)(ws + tmp0);
    unsigned int* y1h = (unsigned int*)(ws + tmp0);
    float* h  = (float*)(ws + align256(tmp0 + (size_t)N * 8 * 4));
    float* y2 = (float*)(ws + align256(tmp0 + (size_t)N * 8 * 4 + (size_t)N * F1 * 4));

    hipMemsetAsync(d_ws, 0, zero_bytes, stream);

    const int B = 256;
    const int nbN = (N + B - 1) / B;           // 391
    const int nbD = ((E >> 2) + B - 1) / B;    // 6250
    const int nbW = (N + 3) / 4;               // 25000 (one wave per row)

    deg_kernel<<<nbD, B, 0, stream>>>(rows, E, deg);
    scan1_kernel<<<nbN, B, 0, stream>>>(deg, parts, N);
    scan2_kernel<<<1, 1024, 0, stream>>>(parts, nbN, rowptr, N, E);
    scan3_kernel<<<nbN, B, 0, stream>>>(deg, parts, rowptr, dinv, N);
    passA_kernel<<<nj, 512, 0, stream>>>(rows, cols, lbt, csrtmp, E, K);
    passB_kernel<<<K, B, 0, stream>>>(lbt, csrtmp, rowptr, csr, N, K, E, nj);
    xw1_kernel<<<nbN, B, 0, stream>>>(x, W1, dinv, y1h, N);
    gather16_kernel<<<nbW, B, 0, stream>>>(rowptr, csr, y1h, dinv, b1, h, N);
    hw2_kernel<<<nbN, B, 0, stream>>>(h, W2, dinv, y2, N);
    gather2_kernel<<<nbW, B, 0, stream>>>(rowptr, csr, y2, dinv, b2, out, N);
}

// Round 9
// 307.472 us; speedup vs baseline: 1.8292x; 1.8292x over previous
//
#include <hip/hip_runtime.h>
#include <math.h>

// GCN forward: 2x GCNConv (20->16->2) + ReLU + log_softmax
// N=100000 nodes, E=6400000 edges.
//
// Per layer (exact algebra of PyG GCNConv w/ self-loops):
//   y[i]   = (x[i] @ W) * dinv[i]
//   s[i]   = sum_{c in in-neighbors(i)} y[c]     (row-sorted CSR, register accum, NO atomics)
//   out[i] = dinv[i]*(s[i] + y[i]) + b           (self-loop = dinv^2 * xw)
//
// Contention/amplification lessons baked in:
//   - R3/R8: device-scope global atomics migrate lines across XCDs through
//     HBM (~32B writeback per atomic when standalone). A 6.4M-atomic global
//     histogram costs 255us/200MB as its own kernel -> NEVER compute deg
//     via global atomics; recover it inside the bucket sort (per-block
//     counts -> padded bhist; in-bucket dcnt in LDS).
//   - R4: per-edge-per-feature LDS float atomics are a wall -> row-sort once.
//   - R5/R6/R7: ANY scattered 4B global writes suffer 4-7x HBM write
//     amplification under concurrent streaming reads. Only coalesced bursts
//     are amp=1. passA scatters into a 64KB LDS stage and bursts out.
//     (Exception: passB's placement into its private 32KB csr region
//     completes fast enough -> measured amp=1.0 in R7.)
//   - R6: y1 gather table in bf16 (3.2MB) -> fits per-XCD 4MiB L2.
//
// Pipeline: passA (LDS-staged multisplit -> block-major csrtmp + lbt + padded
//   bhist) -> bscan (bbase) -> passB (stitch + in-bucket count/sort ->
//   row-sorted csr + rowptr + dinv) -> xw1(bf16) -> gather16 -> hw2 -> gather2.

#define XF 20
#define F1 16
#define F2 2
#define RPB 128           // rows per bucket (1<<7)
#define KMAX 800          // max buckets (N <= 102400)
#define KP   784          // lbt row stride (>= K+1)
#define TILE 16384        // edges per passA block
#define NJMAX 400         // max passA blocks/segments (E <= 6553600)
#define CAP 9216          // passB LDS stage (mean 8192, sigma ~90 -> +11 sigma)
#define BPAD 16           // bhist padding: 1 counter per 64B line

__device__ __forceinline__ unsigned bf16rne(float f) {
    unsigned u = __float_as_uint(f);
    return (u + 0x7FFFu + ((u >> 16) & 1u)) >> 16;
}
__device__ __forceinline__ float bflo(unsigned w) { return __uint_as_float(w << 16); }
__device__ __forceinline__ float bfhi(unsigned w) { return __uint_as_float(w & 0xFFFF0000u); }

// Multisplit with LDS staging: per-block LDS hist -> local scan -> scatter
// packed (c<<7)|(r&127) into 64KB LDS stage (bucket-major) -> coalesced BURST
// to csrtmp[e0..e1] (amp=1 by construction). Side outputs: lbt[blk][k] =
// local bucket start (entry K = tile count), bhist[k*BPAD] += count (padded).
__global__ __launch_bounds__(512) void passA_kernel(const int* __restrict__ rows,
                                                    const int* __restrict__ cols,
                                                    int* __restrict__ bhist,
                                                    int* __restrict__ lbt,
                                                    unsigned int* __restrict__ csrtmp,
                                                    int E, int K) {
    __shared__ unsigned int stage[TILE];  // 64KB
    __shared__ int hist[KMAX];            // counts -> cursors
    __shared__ int tsum[512];
    int t = threadIdx.x;
    int bj = blockIdx.x;
    for (int k = t; k < K; k += 512) hist[k] = 0;
    __syncthreads();
    int e0 = bj * TILE;
    int e1 = min(e0 + TILE, E);
    int n = e1 - e0;
    for (int e = e0 + t; e < e1; e += 512)
        atomicAdd(&hist[rows[e] >> 7], 1);
    __syncthreads();
    // block-wide exclusive scan over K buckets (2 per thread)
    int k0 = 2 * t, k1 = 2 * t + 1;
    int v0 = (k0 < K) ? hist[k0] : 0;
    int v1 = (k1 < K) ? hist[k1] : 0;
    int s = v0 + v1;
    tsum[t] = s;
    __syncthreads();
    for (int d = 1; d < 512; d <<= 1) {
        int u = (t >= d) ? tsum[t - d] : 0;
        __syncthreads();
        tsum[t] += u;
        __syncthreads();
    }
    int run = tsum[t] - s;
    long long lrow = (long long)bj * KP;
    if (k0 < K) {
        hist[k0] = run;  lbt[lrow + k0] = run;
        if (v0) atomicAdd(&bhist[k0 * BPAD], v0);
    }
    if (k1 < K) {
        hist[k1] = run + v0;  lbt[lrow + k1] = run + v0;
        if (v1) atomicAdd(&bhist[k1 * BPAD], v1);
    }
    if (t == 0) lbt[lrow + K] = n;
    __syncthreads();
    // scatter into LDS stage (cursor = hist)
    for (int e = e0 + t; e < e1; e += 512) {
        int r = rows[e];
        int b = r >> 7;
        int pos = atomicAdd(&hist[b], 1);
        stage[pos] = ((unsigned int)cols[e] << 7) | (unsigned int)(r & 127);
    }
    __syncthreads();
    // coalesced burst out
    for (int ss = t; ss < n; ss += 512)
        csrtmp[(size_t)e0 + ss] = stage[ss];
}

// One block; 256 threads x 8 consecutive buckets each -> exclusive scan of
// the padded global histogram into bbase.
__global__ void bscan_kernel(const int* __restrict__ bhist, int K, int E,
                             int* __restrict__ bbase) {
    __shared__ int tsum[256];
    int t = threadIdx.x;
    int vals[8];
    int s = 0;
    #pragma unroll
    for (int j = 0; j < 8; j++) {
        int idx = t * 8 + j;
        vals[j] = (idx < K) ? bhist[idx * BPAD] : 0;
        s += vals[j];
    }
    tsum[t] = s;
    __syncthreads();
    for (int d = 1; d < 256; d <<= 1) {
        int u = (t >= d) ? tsum[t - d] : 0;
        __syncthreads();
        tsum[t] += u;
        __syncthreads();
    }
    int run = tsum[t] - s;
    #pragma unroll
    for (int j = 0; j < 8; j++) {
        int idx = t * 8 + j;
        if (idx < K) bbase[idx] = run;
        run += vals[j];
    }
    if (t == 0) bbase[K] = E;
}

// One block per bucket: load all segment offsets up-front (no dependent
// chains), prefix-scan lengths -> stage positions, burst-gather segments into
// LDS while counting rows (dcnt), wave-scan -> rowptr/dinv/rp, then place
// row-sorted into final csr (writes confined to this bucket's 32KB region).
__global__ __launch_bounds__(256) void passB_kernel(const int* __restrict__ lbt,
                                                    const unsigned int* __restrict__ csrtmp,
                                                    const int* __restrict__ bbase,
                                                    unsigned int* __restrict__ csr,
                                                    int* __restrict__ rowptr,
                                                    float* __restrict__ dinv,
                                                    int N, int K, int E, int nj) {
    __shared__ unsigned int stage[CAP];
    __shared__ int segoff[NJMAX];
    __shared__ int stagepos[NJMAX + 1];
    __shared__ int dcnt[RPB];
    __shared__ int rp[RPB];
    __shared__ int cur[RPB];
    __shared__ int tsum[256];
    int b = blockIdx.x, t = threadIdx.x;
    int lo = b << 7;
    if (t < RPB) { dcnt[t] = 0; cur[t] = 0; }
    // load 2 segments per thread: offsets (8B contiguous read per seg)
    int a0 = 2 * t, a1 = 2 * t + 1;
    int la = 0, lb2 = 0;
    if (a0 < nj) {
        const int* lp = lbt + (long long)a0 * KP + b;
        int o0 = lp[0], o1 = lp[1];
        segoff[a0] = o0; la = o1 - o0;
    }
    if (a1 < nj) {
        const int* lp = lbt + (long long)a1 * KP + b;
        int o0 = lp[0], o1 = lp[1];
        segoff[a1] = o0; lb2 = o1 - o0;
    }
    int s = la + lb2;
    tsum[t] = s;
    __syncthreads();
    for (int d = 1; d < 256; d <<= 1) {
        int u = (t >= d) ? tsum[t - d] : 0;
        __syncthreads();
        tsum[t] += u;
        __syncthreads();
    }
    int run = tsum[t] - s;
    if (a0 < nj) stagepos[a0] = run;
    if (a1 < nj) stagepos[a1] = run + la;
    if (t == 255) stagepos[nj] = tsum[255];
    __syncthreads();
    int cnt = min(stagepos[nj], CAP);
    // stage-in + row count: 8 sub-waves of 32 lanes, segments round-robin
    int sw = t >> 5, ln = t & 31;
    for (int seg = sw; seg < nj; seg += 8) {
        int sp = stagepos[seg];
        int len = stagepos[seg + 1] - sp;
        if (sp + len > CAP) len = max(0, CAP - sp);  // safety clamp
        size_t src = (size_t)seg * TILE + segoff[seg];
        for (int e2 = ln; e2 < len; e2 += 32) {
            unsigned int p = csrtmp[src + e2];
            stage[sp + e2] = p;
            atomicAdd(&dcnt[p & 127u], 1);
        }
    }
    __syncthreads();
    int gb = bbase[b];
    if (t < 64) {  // one wave scans 128 counters, 2 per lane
        int v0 = dcnt[2 * t], v1 = dcnt[2 * t + 1];
        int ss = v0 + v1;
        int sc = ss;
        #pragma unroll
        for (int d = 1; d < 64; d <<= 1) {
            int u = __shfl_up(sc, d);
            if (t >= d) sc += u;
        }
        int excl = gb + sc - ss;
        rp[2 * t] = excl;
        rp[2 * t + 1] = excl + v0;
        int i0 = lo + 2 * t, i1 = i0 + 1;
        if (i0 < N) { rowptr[i0] = excl;      dinv[i0] = rsqrtf((float)v0 + 1.0f); }
        if (i1 < N) { rowptr[i1] = excl + v0; dinv[i1] = rsqrtf((float)v1 + 1.0f); }
        if (t == 0 && b == K - 1) rowptr[N] = E;
    }
    __syncthreads();
    for (int ss = t; ss < cnt; ss += 256) {
        unsigned int p = stage[ss];
        int rr = (int)(p & 127u);
        int dst = rp[rr] + atomicAdd(&cur[rr], 1);
        csr[dst] = p >> 7;
    }
}

// y1h[i][j] = bf16( (sum_k x[i][k] * W1[k][j]) * dinv[i] )  -- 32B/row table
__global__ void xw1_kernel(const float* __restrict__ x, const float* __restrict__ W1,
                           const float* __restrict__ dinv, unsigned int* __restrict__ y1h,
                           int N) {
    __shared__ float Ws[XF * F1];
    for (int k = threadIdx.x; k < XF * F1; k += blockDim.x) Ws[k] = W1[k];
    __syncthreads();
    int i = blockIdx.x * blockDim.x + threadIdx.x;
    if (i >= N) return;
    const float4* xv = (const float4*)(x + (size_t)i * XF);
    float xr[XF];
    #pragma unroll
    for (int q = 0; q < 5; q++) {
        float4 v = xv[q];
        xr[q*4+0] = v.x; xr[q*4+1] = v.y; xr[q*4+2] = v.z; xr[q*4+3] = v.w;
    }
    float d = dinv[i];
    float out[F1];
    #pragma unroll
    for (int j = 0; j < F1; j++) {
        float a = 0.f;
        #pragma unroll
        for (int k = 0; k < XF; k++) a += xr[k] * Ws[k * F1 + j];
        out[j] = a * d;
    }
    unsigned int w[8];
    #pragma unroll
    for (int q = 0; q < 8; q++)
        w[q] = bf16rne(out[2*q]) | (bf16rne(out[2*q+1]) << 16);
    uint4* o = (uint4*)(y1h + (size_t)i * 8);
    o[0] = make_uint4(w[0], w[1], w[2], w[3]);
    o[1] = make_uint4(w[4], w[5], w[6], w[7]);
}

// One wave per row: 2 lanes/edge (8 bf16 features each), 32 edges in flight,
// register accumulation, shfl-xor reduce, fused ReLU. Zero atomics.
__global__ __launch_bounds__(256) void gather16_kernel(const int* __restrict__ rowptr,
                                                       const unsigned int* __restrict__ csr,
                                                       const unsigned int* __restrict__ y1h,
                                                       const float* __restrict__ dinv,
                                                       const float* __restrict__ b1,
                                                       float* __restrict__ h, int N) {
    int wave = threadIdx.x >> 6;
    int lane = threadIdx.x & 63;
    int i = blockIdx.x * 4 + wave;
    if (i >= N) return;
    int half = lane & 1, es = lane >> 1;
    int start = rowptr[i], end = rowptr[i + 1];
    const uint4* Y = (const uint4*)y1h;
    float acc[8] = {0.f, 0.f, 0.f, 0.f, 0.f, 0.f, 0.f, 0.f};
    for (int slot = start + es; slot < end; slot += 32) {
        int c = (int)csr[slot];
        uint4 w = Y[(size_t)c * 2 + half];
        acc[0] += bflo(w.x); acc[1] += bfhi(w.x);
        acc[2] += bflo(w.y); acc[3] += bfhi(w.y);
        acc[4] += bflo(w.z); acc[5] += bfhi(w.z);
        acc[6] += bflo(w.w); acc[7] += bfhi(w.w);
    }
    #pragma unroll
    for (int m = 2; m <= 32; m <<= 1) {
        #pragma unroll
        for (int k = 0; k < 8; k++) acc[k] += __shfl_xor(acc[k], m);
    }
    if (lane < 2) {
        float d = dinv[i];
        uint4 w = Y[(size_t)i * 2 + lane];
        float self[8] = { bflo(w.x), bfhi(w.x), bflo(w.y), bfhi(w.y),
                          bflo(w.z), bfhi(w.z), bflo(w.w), bfhi(w.w) };
        float4 bl = ((const float4*)b1)[lane * 2];
        float4 bh = ((const float4*)b1)[lane * 2 + 1];
        float bb[8] = { bl.x, bl.y, bl.z, bl.w, bh.x, bh.y, bh.z, bh.w };
        float v[8];
        #pragma unroll
        for (int k = 0; k < 8; k++)
            v[k] = fmaxf(d * (acc[k] + self[k]) + bb[k], 0.f);
        float4* ho = (float4*)(h + (size_t)i * F1 + lane * 8);
        ho[0] = make_float4(v[0], v[1], v[2], v[3]);
        ho[1] = make_float4(v[4], v[5], v[6], v[7]);
    }
}

// y2[i][j] = (sum_k h[i][k] * W2[k][j]) * dinv[i]
__global__ void hw2_kernel(const float* __restrict__ h, const float* __restrict__ W2,
                           const float* __restrict__ dinv, float* __restrict__ y2, int N) {
    __shared__ float Ws[F1 * F2];
    if (threadIdx.x < F1 * F2) Ws[threadIdx.x] = W2[threadIdx.x];
    __syncthreads();
    int i = blockIdx.x * blockDim.x + threadIdx.x;
    if (i >= N) return;
    const float4* hv = (const float4*)(h + (size_t)i * F1);
    float a0 = 0.f, a1 = 0.f;
    #pragma unroll
    for (int q = 0; q < 4; q++) {
        float4 v = hv[q];
        a0 += v.x * Ws[(q*4+0)*2] + v.y * Ws[(q*4+1)*2] + v.z * Ws[(q*4+2)*2] + v.w * Ws[(q*4+3)*2];
        a1 += v.x * Ws[(q*4+0)*2+1] + v.y * Ws[(q*4+1)*2+1] + v.z * Ws[(q*4+2)*2+1] + v.w * Ws[(q*4+3)*2+1];
    }
    float d = dinv[i];
    ((float2*)y2)[i] = make_float2(a0 * d, a1 * d);
}

// One wave per row: 1 lane/edge float2 gather, register accum, shfl reduce,
// fused log_softmax. Zero atomics. y2 = 800KB -> L2-resident.
__global__ __launch_bounds__(256) void gather2_kernel(const int* __restrict__ rowptr,
                                                      const unsigned int* __restrict__ csr,
                                                      const float* __restrict__ y2,
                                                      const float* __restrict__ dinv,
                                                      const float* __restrict__ b2,
                                                      float* __restrict__ out, int N) {
    int wave = threadIdx.x >> 6;
    int lane = threadIdx.x & 63;
    int i = blockIdx.x * 4 + wave;
    if (i >= N) return;
    int start = rowptr[i], end = rowptr[i + 1];
    float a0 = 0.f, a1 = 0.f;
    for (int slot = start + lane; slot < end; slot += 64) {
        int c = (int)csr[slot];
        float2 v = ((const float2*)y2)[c];
        a0 += v.x;
        a1 += v.y;
    }
    #pragma unroll
    for (int m = 32; m > 0; m >>= 1) {
        a0 += __shfl_xor(a0, m);
        a1 += __shfl_xor(a1, m);
    }
    if (lane == 0) {
        float d = dinv[i];
        float2 yi = ((const float2*)y2)[i];
        float v0 = d * (a0 + yi.x) + b2[0];
        float v1 = d * (a1 + yi.y) + b2[1];
        float mm = fmaxf(v0, v1);
        float lse = mm + logf(expf(v0 - mm) + expf(v1 - mm));
        ((float2*)out)[i] = make_float2(v0 - lse, v1 - lse);
    }
}

static inline size_t align256(size_t x) { return (x + 255) & ~(size_t)255; }

extern "C" void kernel_launch(void* const* d_in, const int* in_sizes, int n_in,
                              void* d_out, int out_size, void* d_ws, size_t ws_size,
                              hipStream_t stream) {
    const float* x  = (const float*)d_in[0];
    const int*   ei = (const int*)d_in[1];
    const float* W1 = (const float*)d_in[2];
    const float* b1 = (const float*)d_in[3];
    const float* W2 = (const float*)d_in[4];
    const float* b2 = (const float*)d_in[5];
    float* out = (float*)d_out;

    const int N = in_sizes[0] / XF;
    const int E = in_sizes[1] / 2;
    const int* rows = ei;
    const int* cols = ei + E;
    const int K = (N + RPB - 1) >> 7;        // 782 buckets for N=100000
    const int nj = (E + TILE - 1) / TILE;    // 391 passA blocks/segments

    // Workspace; zero-region first (padded bhist, 51KB memset).
    char* ws = (char*)d_ws;
    size_t off = 0;
    int*   bhist   = (int*)(ws + off);   off = align256(off + (size_t)KMAX * BPAD * 4);
    size_t zero_bytes = off;
    int*   bbase   = (int*)(ws + off);   off = align256(off + (size_t)(KMAX + 1) * 4);
    int*   rowptr  = (int*)(ws + off);   off = align256(off + (size_t)(N + 1) * 4);
    float* dinv    = (float*)(ws + off); off = align256(off + (size_t)N * 4);
    int*   lbt     = (int*)(ws + off);   off = align256(off + (size_t)nj * KP * 4);
    unsigned int* csr = (unsigned int*)(ws + off); off = align256(off + (size_t)E * 4);
    // csrtmp is dead after passB -> y1h/h/y2 alias its region.
    size_t tmp0 = off;
    unsigned int* csrtmp = (unsigned int*)(ws + tmp0);
    unsigned int* y1h = (unsigned int*)(ws + tmp0);
    float* h  = (float*)(ws + align256(tmp0 + (size_t)N * 8 * 4));
    float* y2 = (float*)(ws + align256(tmp0 + (size_t)N * 8 * 4 + (size_t)N * F1 * 4));

    hipMemsetAsync(d_ws, 0, zero_bytes, stream);

    const int B = 256;
    const int nbN = (N + B - 1) / B;   // 391
    const int nbW = (N + 3) / 4;       // 25000 (one wave per row)

    passA_kernel<<<nj, 512, 0, stream>>>(rows, cols, bhist, lbt, csrtmp, E, K);
    bscan_kernel<<<1, B, 0, stream>>>(bhist, K, E, bbase);
    passB_kernel<<<K, B, 0, stream>>>(lbt, csrtmp, bbase, csr, rowptr, dinv, N, K, E, nj);
    xw1_kernel<<<nbN, B, 0, stream>>>(x, W1, dinv, y1h, N);
    gather16_kernel<<<nbW, B, 0, stream>>>(rowptr, csr, y1h, dinv, b1, h, N);
    hw2_kernel<<<nbN, B, 0, stream>>>(h, W2, dinv, y2, N);
    gather2_kernel<<<nbW, B, 0, stream>>>(rowptr, csr, y2, dinv, b2, out, N);
}

// Round 10
// 282.000 us; speedup vs baseline: 1.9944x; 1.0903x over previous
//
#include <hip/hip_runtime.h>
#include <math.h>

// GCN forward: 2x GCNConv (20->16->2) + ReLU + log_softmax
// N=100000 nodes, E=6400000 edges.
//
// Per layer (exact algebra of PyG GCNConv w/ self-loops):
//   y[i]   = (x[i] @ W) * dinv[i]
//   s[i]   = sum_{c in in-neighbors(i)} y[c]     (row-sorted CSR, register accum, NO atomics)
//   out[i] = dinv[i]*(s[i] + y[i]) + b           (self-loop = dinv^2 * xw)
//
// Contention/amplification lessons baked in:
//   - R3/R8: device-scope global atomics migrate lines across XCDs through
//     HBM. A 6.4M-atomic global histogram costs 255us/200MB standalone ->
//     recover degree inside the bucket sort (padded bhist + in-bucket dcnt).
//   - R4: per-edge-per-feature LDS float atomics are a wall -> row-sort once.
//   - R5/R6/R7: scattered 4B global writes suffer 4-7x HBM write
//     amplification under streaming reads. Only coalesced bursts are amp=1.
//     passA scatters into a 64KB LDS stage and bursts out. (Exception:
//     passB's placement into its private 32KB csr region: measured amp=1.0.)
//   - R6: y1 gather table in bf16 (3.2MB) -> fits per-XCD 4MiB L2.
//   - R9: passB is LATENCY-bound (HBM 11%, VALU 9%): short 84B segment
//     reads, few in flight. R10: 512 threads, 16-lane sub-segments -> 32
//     segments in flight; passA holds rows in registers (one less 25.6MB
//     read pass).
//
// Pipeline: passA (reg-held multisplit -> block-major csrtmp + lbt + padded
//   bhist) -> bscan (bbase) -> passB (stitch + in-bucket count/sort ->
//   row-sorted csr + rowptr + dinv) -> xw1(bf16) -> gather16 -> hw2 -> gather2.

#define XF 20
#define F1 16
#define F2 2
#define RPB 128           // rows per bucket (1<<7)
#define KMAX 800          // max buckets (N <= 102400)
#define KP   784          // lbt row stride (>= K+1)
#define TILE 16384        // edges per passA block
#define EPT 32            // edges per passA thread (TILE/512)
#define NJMAX 400         // max passA blocks/segments (E <= 6553600)
#define CAP 9216          // passB LDS stage (mean 8184, sigma ~90 -> +11 sigma)
#define BPAD 16           // bhist padding: 1 counter per 64B line

__device__ __forceinline__ unsigned bf16rne(float f) {
    unsigned u = __float_as_uint(f);
    return (u + 0x7FFFu + ((u >> 16) & 1u)) >> 16;
}
__device__ __forceinline__ float bflo(unsigned w) { return __uint_as_float(w << 16); }
__device__ __forceinline__ float bfhi(unsigned w) { return __uint_as_float(w & 0xFFFF0000u); }

// Multisplit with LDS staging: rows held in registers across hist+scatter
// phases (single read of rows). Scatter packed (c<<7)|(r&127) into 64KB LDS
// stage (bucket-major) -> coalesced BURST to csrtmp[e0..e1] (amp=1).
// Side outputs: lbt[blk][k] = local bucket start (entry K = tile count),
// bhist[k*BPAD] += count (padded global atomics).
__global__ __launch_bounds__(512) void passA_kernel(const int* __restrict__ rows,
                                                    const int* __restrict__ cols,
                                                    int* __restrict__ bhist,
                                                    int* __restrict__ lbt,
                                                    unsigned int* __restrict__ csrtmp,
                                                    int E, int K) {
    __shared__ unsigned int stage[TILE];  // 64KB
    __shared__ int hist[KMAX];            // counts -> cursors
    __shared__ int tsum[512];
    int t = threadIdx.x;
    int bj = blockIdx.x;
    for (int k = t; k < K; k += 512) hist[k] = 0;
    __syncthreads();
    int e0 = bj * TILE;
    int e1 = min(e0 + TILE, E);
    int n = e1 - e0;
    // phase 1: read rows once, hold in registers, build LDS histogram
    int rloc[EPT];
    #pragma unroll
    for (int it = 0; it < EPT; it++) {
        int e = e0 + it * 512 + t;
        if (e < e1) {
            int r = rows[e];
            rloc[it] = r;
            atomicAdd(&hist[r >> 7], 1);
        }
    }
    __syncthreads();
    // block-wide exclusive scan over K buckets (2 per thread)
    int k0 = 2 * t, k1 = 2 * t + 1;
    int v0 = (k0 < K) ? hist[k0] : 0;
    int v1 = (k1 < K) ? hist[k1] : 0;
    int s = v0 + v1;
    tsum[t] = s;
    __syncthreads();
    for (int d = 1; d < 512; d <<= 1) {
        int u = (t >= d) ? tsum[t - d] : 0;
        __syncthreads();
        tsum[t] += u;
        __syncthreads();
    }
    int run = tsum[t] - s;
    long long lrow = (long long)bj * KP;
    if (k0 < K) {
        hist[k0] = run;  lbt[lrow + k0] = run;
        if (v0) atomicAdd(&bhist[k0 * BPAD], v0);
    }
    if (k1 < K) {
        hist[k1] = run + v0;  lbt[lrow + k1] = run + v0;
        if (v1) atomicAdd(&bhist[k1 * BPAD], v1);
    }
    if (t == 0) lbt[lrow + K] = n;
    __syncthreads();
    // phase 2: scatter into LDS stage using register-held rows + fresh cols
    #pragma unroll
    for (int it = 0; it < EPT; it++) {
        int e = e0 + it * 512 + t;
        if (e < e1) {
            int r = rloc[it];
            int c = cols[e];
            int pos = atomicAdd(&hist[r >> 7], 1);
            stage[pos] = ((unsigned int)c << 7) | (unsigned int)(r & 127);
        }
    }
    __syncthreads();
    // coalesced burst out
    for (int ss = t; ss < n; ss += 512)
        csrtmp[(size_t)e0 + ss] = stage[ss];
}

// One block; 256 threads x 8 consecutive buckets each -> exclusive scan of
// the padded global histogram into bbase.
__global__ void bscan_kernel(const int* __restrict__ bhist, int K, int E,
                             int* __restrict__ bbase) {
    __shared__ int tsum[256];
    int t = threadIdx.x;
    int vals[8];
    int s = 0;
    #pragma unroll
    for (int j = 0; j < 8; j++) {
        int idx = t * 8 + j;
        vals[j] = (idx < K) ? bhist[idx * BPAD] : 0;
        s += vals[j];
    }
    tsum[t] = s;
    __syncthreads();
    for (int d = 1; d < 256; d <<= 1) {
        int u = (t >= d) ? tsum[t - d] : 0;
        __syncthreads();
        tsum[t] += u;
        __syncthreads();
    }
    int run = tsum[t] - s;
    #pragma unroll
    for (int j = 0; j < 8; j++) {
        int idx = t * 8 + j;
        if (idx < K) bbase[idx] = run;
        run += vals[j];
    }
    if (t == 0) bbase[K] = E;
}

// One block per bucket, 512 threads: load all segment offsets up-front
// (1/thread), prefix-scan lengths -> stage positions, stitch segments with
// 16-lane sub-waves (32 segments in flight), count rows while staging,
// wave-scan -> rowptr/dinv/rp, place row-sorted into final csr.
__global__ __launch_bounds__(512) void passB_kernel(const int* __restrict__ lbt,
                                                    const unsigned int* __restrict__ csrtmp,
                                                    const int* __restrict__ bbase,
                                                    unsigned int* __restrict__ csr,
                                                    int* __restrict__ rowptr,
                                                    float* __restrict__ dinv,
                                                    int N, int K, int E, int nj) {
    __shared__ unsigned int stage[CAP];
    __shared__ int segoff[NJMAX];
    __shared__ int stagepos[NJMAX + 1];
    __shared__ int dcnt[RPB];
    __shared__ int rp[RPB];
    __shared__ int cur[RPB];
    __shared__ int tsum[512];
    int b = blockIdx.x, t = threadIdx.x;
    int lo = b << 7;
    if (t < RPB) { dcnt[t] = 0; cur[t] = 0; }
    // one segment per thread (nj <= 400 < 512)
    int la = 0;
    if (t < nj) {
        const int* lp = lbt + (long long)t * KP + b;
        int o0 = lp[0], o1 = lp[1];
        segoff[t] = o0; la = o1 - o0;
    }
    tsum[t] = la;
    __syncthreads();
    for (int d = 1; d < 512; d <<= 1) {
        int u = (t >= d) ? tsum[t - d] : 0;
        __syncthreads();
        tsum[t] += u;
        __syncthreads();
    }
    if (t < nj) stagepos[t] = tsum[t] - la;
    if (t == 511) stagepos[nj] = tsum[511];
    __syncthreads();
    int cnt = min(stagepos[nj], CAP);
    // stitch: 32 sub-waves of 16 lanes, segments round-robin
    int sw = t >> 4, ln = t & 15;
    for (int seg = sw; seg < nj; seg += 32) {
        int sp = stagepos[seg];
        int len = stagepos[seg + 1] - sp;
        if (sp + len > CAP) len = max(0, CAP - sp);  // safety clamp
        size_t src = (size_t)seg * TILE + segoff[seg];
        for (int e2 = ln; e2 < len; e2 += 16) {
            unsigned int p = csrtmp[src + e2];
            stage[sp + e2] = p;
            atomicAdd(&dcnt[p & 127u], 1);
        }
    }
    __syncthreads();
    int gb = bbase[b];
    if (t < 64) {  // one wave scans 128 counters, 2 per lane
        int v0 = dcnt[2 * t], v1 = dcnt[2 * t + 1];
        int ss = v0 + v1;
        int sc = ss;
        #pragma unroll
        for (int d = 1; d < 64; d <<= 1) {
            int u = __shfl_up(sc, d);
            if (t >= d) sc += u;
        }
        int excl = gb + sc - ss;
        rp[2 * t] = excl;
        rp[2 * t + 1] = excl + v0;
        int i0 = lo + 2 * t, i1 = i0 + 1;
        if (i0 < N) { rowptr[i0] = excl;      dinv[i0] = rsqrtf((float)v0 + 1.0f); }
        if (i1 < N) { rowptr[i1] = excl + v0; dinv[i1] = rsqrtf((float)v1 + 1.0f); }
        if (t == 0 && b == K - 1) rowptr[N] = E;
    }
    __syncthreads();
    // row-sorted placement (writes confined to this bucket's 32KB region;
    // measured amp=1.0 in R7)
    for (int ss = t; ss < cnt; ss += 512) {
        unsigned int p = stage[ss];
        int rr = (int)(p & 127u);
        int dst = rp[rr] + atomicAdd(&cur[rr], 1);
        csr[dst] = p >> 7;
    }
}

// y1h[i][j] = bf16( (sum_k x[i][k] * W1[k][j]) * dinv[i] )  -- 32B/row table
__global__ void xw1_kernel(const float* __restrict__ x, const float* __restrict__ W1,
                           const float* __restrict__ dinv, unsigned int* __restrict__ y1h,
                           int N) {
    __shared__ float Ws[XF * F1];
    for (int k = threadIdx.x; k < XF * F1; k += blockDim.x) Ws[k] = W1[k];
    __syncthreads();
    int i = blockIdx.x * blockDim.x + threadIdx.x;
    if (i >= N) return;
    const float4* xv = (const float4*)(x + (size_t)i * XF);
    float xr[XF];
    #pragma unroll
    for (int q = 0; q < 5; q++) {
        float4 v = xv[q];
        xr[q*4+0] = v.x; xr[q*4+1] = v.y; xr[q*4+2] = v.z; xr[q*4+3] = v.w;
    }
    float d = dinv[i];
    float out[F1];
    #pragma unroll
    for (int j = 0; j < F1; j++) {
        float a = 0.f;
        #pragma unroll
        for (int k = 0; k < XF; k++) a += xr[k] * Ws[k * F1 + j];
        out[j] = a * d;
    }
    unsigned int w[8];
    #pragma unroll
    for (int q = 0; q < 8; q++)
        w[q] = bf16rne(out[2*q]) | (bf16rne(out[2*q+1]) << 16);
    uint4* o = (uint4*)(y1h + (size_t)i * 8);
    o[0] = make_uint4(w[0], w[1], w[2], w[3]);
    o[1] = make_uint4(w[4], w[5], w[6], w[7]);
}

// One wave per row: 2 lanes/edge (8 bf16 features each), 32 edges in flight,
// register accumulation, shfl-xor reduce, fused ReLU. Zero atomics.
__global__ __launch_bounds__(256) void gather16_kernel(const int* __restrict__ rowptr,
                                                       const unsigned int* __restrict__ csr,
                                                       const unsigned int* __restrict__ y1h,
                                                       const float* __restrict__ dinv,
                                                       const float* __restrict__ b1,
                                                       float* __restrict__ h, int N) {
    int wave = threadIdx.x >> 6;
    int lane = threadIdx.x & 63;
    int i = blockIdx.x * 4 + wave;
    if (i >= N) return;
    int half = lane & 1, es = lane >> 1;
    int start = rowptr[i], end = rowptr[i + 1];
    const uint4* Y = (const uint4*)y1h;
    float acc[8] = {0.f, 0.f, 0.f, 0.f, 0.f, 0.f, 0.f, 0.f};
    for (int slot = start + es; slot < end; slot += 32) {
        int c = (int)csr[slot];
        uint4 w = Y[(size_t)c * 2 + half];
        acc[0] += bflo(w.x); acc[1] += bfhi(w.x);
        acc[2] += bflo(w.y); acc[3] += bfhi(w.y);
        acc[4] += bflo(w.z); acc[5] += bfhi(w.z);
        acc[6] += bflo(w.w); acc[7] += bfhi(w.w);
    }
    #pragma unroll
    for (int m = 2; m <= 32; m <<= 1) {
        #pragma unroll
        for (int k = 0; k < 8; k++) acc[k] += __shfl_xor(acc[k], m);
    }
    if (lane < 2) {
        float d = dinv[i];
        uint4 w = Y[(size_t)i * 2 + lane];
        float self[8] = { bflo(w.x), bfhi(w.x), bflo(w.y), bfhi(w.y),
                          bflo(w.z), bfhi(w.z), bflo(w.w), bfhi(w.w) };
        float4 bl = ((const float4*)b1)[lane * 2];
        float4 bh = ((const float4*)b1)[lane * 2 + 1];
        float bb[8] = { bl.x, bl.y, bl.z, bl.w, bh.x, bh.y, bh.z, bh.w };
        float v[8];
        #pragma unroll
        for (int k = 0; k < 8; k++)
            v[k] = fmaxf(d * (acc[k] + self[k]) + bb[k], 0.f);
        float4* ho = (float4*)(h + (size_t)i * F1 + lane * 8);
        ho[0] = make_float4(v[0], v[1], v[2], v[3]);
        ho[1] = make_float4(v[4], v[5], v[6], v[7]);
    }
}

// y2[i][j] = (sum_k h[i][k] * W2[k][j]) * dinv[i]
__global__ void hw2_kernel(const float* __restrict__ h, const float* __restrict__ W2,
                           const float* __restrict__ dinv, float* __restrict__ y2, int N) {
    __shared__ float Ws[F1 * F2];
    if (threadIdx.x < F1 * F2) Ws[threadIdx.x] = W2[threadIdx.x];
    __syncthreads();
    int i = blockIdx.x * blockDim.x + threadIdx.x;
    if (i >= N) return;
    const float4* hv = (const float4*)(h + (size_t)i * F1);
    float a0 = 0.f, a1 = 0.f;
    #pragma unroll
    for (int q = 0; q < 4; q++) {
        float4 v = hv[q];
        a0 += v.x * Ws[(q*4+0)*2] + v.y * Ws[(q*4+1)*2] + v.z * Ws[(q*4+2)*2] + v.w * Ws[(q*4+3)*2];
        a1 += v.x * Ws[(q*4+0)*2+1] + v.y * Ws[(q*4+1)*2+1] + v.z * Ws[(q*4+2)*2+1] + v.w * Ws[(q*4+3)*2+1];
    }
    float d = dinv[i];
    ((float2*)y2)[i] = make_float2(a0 * d, a1 * d);
}

// One wave per row: 1 lane/edge float2 gather, register accum, shfl reduce,
// fused log_softmax. Zero atomics. y2 = 800KB -> L2-resident.
__global__ __launch_bounds__(256) void gather2_kernel(const int* __restrict__ rowptr,
                                                      const unsigned int* __restrict__ csr,
                                                      const float* __restrict__ y2,
                                                      const float* __restrict__ dinv,
                                                      const float* __restrict__ b2,
                                                      float* __restrict__ out, int N) {
    int wave = threadIdx.x >> 6;
    int lane = threadIdx.x & 63;
    int i = blockIdx.x * 4 + wave;
    if (i >= N) return;
    int start = rowptr[i], end = rowptr[i + 1];
    float a0 = 0.f, a1 = 0.f;
    for (int slot = start + lane; slot < end; slot += 64) {
        int c = (int)csr[slot];
        float2 v = ((const float2*)y2)[c];
        a0 += v.x;
        a1 += v.y;
    }
    #pragma unroll
    for (int m = 32; m > 0; m >>= 1) {
        a0 += __shfl_xor(a0, m);
        a1 += __shfl_xor(a1, m);
    }
    if (lane == 0) {
        float d = dinv[i];
        float2 yi = ((const float2*)y2)[i];
        float v0 = d * (a0 + yi.x) + b2[0];
        float v1 = d * (a1 + yi.y) + b2[1];
        float mm = fmaxf(v0, v1);
        float lse = mm + logf(expf(v0 - mm) + expf(v1 - mm));
        ((float2*)out)[i] = make_float2(v0 - lse, v1 - lse);
    }
}

static inline size_t align256(size_t x) { return (x + 255) & ~(size_t)255; }

extern "C" void kernel_launch(void* const* d_in, const int* in_sizes, int n_in,
                              void* d_out, int out_size, void* d_ws, size_t ws_size,
                              hipStream_t stream) {
    const float* x  = (const float*)d_in[0];
    const int*   ei = (const int*)d_in[1];
    const float* W1 = (const float*)d_in[2];
    const float* b1 = (const float*)d_in[3];
    const float* W2 = (const float*)d_in[4];
    const float* b2 = (const float*)d_in[5];
    float* out = (float*)d_out;

    const int N = in_sizes[0] / XF;
    const int E = in_sizes[1] / 2;
    const int* rows = ei;
    const int* cols = ei + E;
    const int K = (N + RPB - 1) >> 7;        // 782 buckets for N=100000
    const int nj = (E + TILE - 1) / TILE;    // 391 passA blocks/segments

    // Workspace; zero-region first (padded bhist, 51KB memset).
    char* ws = (char*)d_ws;
    size_t off = 0;
    int*   bhist   = (int*)(ws + off);   off = align256(off + (size_t)KMAX * BPAD * 4);
    size_t zero_bytes = off;
    int*   bbase   = (int*)(ws + off);   off = align256(off + (size_t)(KMAX + 1) * 4);
    int*   rowptr  = (int*)(ws + off);   off = align256(off + (size_t)(N + 1) * 4);
    float* dinv    = (float*)(ws + off); off = align256(off + (size_t)N * 4);
    int*   lbt     = (int*)(ws + off);   off = align256(off + (size_t)nj * KP * 4);
    unsigned int* csr = (unsigned int*)(ws + off); off = align256(off + (size_t)E * 4);
    // csrtmp is dead after passB -> y1h/h/y2 alias its region.
    size_t tmp0 = off;
    unsigned int* csrtmp = (unsigned int*)(ws + tmp0);
    unsigned int* y1h = (unsigned int*)(ws + tmp0);
    float* h  = (float*)(ws + align256(tmp0 + (size_t)N * 8 * 4));
    float* y2 = (float*)(ws + align256(tmp0 + (size_t)N * 8 * 4 + (size_t)N * F1 * 4));

    hipMemsetAsync(d_ws, 0, zero_bytes, stream);

    const int B = 256;
    const int nbN = (N + B - 1) / B;   // 391
    const int nbW = (N + 3) / 4;       // 25000 (one wave per row)

    passA_kernel<<<nj, 512, 0, stream>>>(rows, cols, bhist, lbt, csrtmp, E, K);
    bscan_kernel<<<1, B, 0, stream>>>(bhist, K, E, bbase);
    passB_kernel<<<K, 512, 0, stream>>>(lbt, csrtmp, bbase, csr, rowptr, dinv, N, K, E, nj);
    xw1_kernel<<<nbN, B, 0, stream>>>(x, W1, dinv, y1h, N);
    gather16_kernel<<<nbW, B, 0, stream>>>(rowptr, csr, y1h, dinv, b1, h, N);
    hw2_kernel<<<nbN, B, 0, stream>>>(h, W2, dinv, y2, N);
    gather2_kernel<<<nbW, B, 0, stream>>>(rowptr, csr, y2, dinv, b2, out, N);
}